// Round 5
// baseline (145.406 us; speedup 1.0000x reference)
//
#include <hip/hip_runtime.h>
#include <math.h>

#define H 256
#define N2 32
#define Bsz 8
#define Lseq 4096
#define BH (Bsz*H)          // 2048 sequences
#define NCH 32              // chunks along L
#define LC (Lseq/NCH)       // 128 chunk length
#define HN (H*N2)           // 8192

// workspace layout (float slots):
//  yb : BH*Lseq bf16        post-GELU activations
//  Wb : 512*256 bf16        pre-converted W
//  Tb : H*128*128 bf16      Toeplitz conv matrix T[h][j][m] = k[h][j-m] (0 if j<m)
//  Eb : H*128*64 bf16       emission basis E[h][j][p]   (j-major, p-contig)
//  Vb : H*64*128 bf16       state basis  V[h][p][j]     (p-major, j-contig)
//  WL : H*64 f32            per-(h,n) chunk propagator wL = w^128 (re,im pairs)
#define Y_OFF  0
#define WB_OFF (Y_OFF + (BH*Lseq/2))
#define TB_OFF (WB_OFF + (512*256/2))
#define EB_OFF (TB_OFF + (H*128*128/2))
#define VB_OFF (EB_OFF + (H*128*64/2))
#define WL_OFF (VB_OFF + (H*64*128/2))

typedef __attribute__((ext_vector_type(8))) short bf16x8;
typedef __attribute__((ext_vector_type(8))) unsigned short u16x8;
typedef __attribute__((ext_vector_type(4))) float f32x4;

__device__ __forceinline__ unsigned short f2bf(float x) {
  union { float f; unsigned int u; } v; v.f = x;
  unsigned int r = v.u + 0x7fffu + ((v.u >> 16) & 1u);  // round-to-nearest-even
  return (unsigned short)(r >> 16);
}
__device__ __forceinline__ unsigned int packbf(float lo, float hi) {
  return (unsigned int)f2bf(lo) | ((unsigned int)f2bf(hi) << 16);
}
__device__ __forceinline__ float bf2f(unsigned short b) {
  union { unsigned int u; float f; } v; v.u = ((unsigned int)b) << 16;
  return v.f;
}
__device__ __forceinline__ float u2f(unsigned int u) {
  union { unsigned int u; float f; } v; v.u = u; return v.f;
}

// ---------------- K0: prep — W->bf16, Toeplitz Tb, bases Eb & Vb, propagator WL ----------------
// grid 256 (h), block 512 = (j 0..127) x (ng 0..3); 8 waves/block = 2 waves/SIMD.
// All transcendentals via native v_exp/v_sin/v_cos (__expf/__sinf/__cosf): the ocml
// libcalls (sincosf with full-range reduction; args reach ~1240 rad) were the dominant
// instruction cost. fp32 arg-scaling error at 1240 rad ~1.5e-4 rad << bf16 quantum.
__global__ __launch_bounds__(512) void k_prep(const float* __restrict__ log_dt,
                                              const float* __restrict__ C,
                                              const float* __restrict__ lar,
                                              const float* __restrict__ aim,
                                              const float* __restrict__ W,
                                              unsigned short* __restrict__ Wb,
                                              unsigned short* __restrict__ Tb,
                                              unsigned short* __restrict__ Eb,
                                              unsigned short* __restrict__ Vb,
                                              float* __restrict__ WLb) {
  __shared__ float kpart[3][128];
  __shared__ unsigned short kbuf[128];
  int h   = blockIdx.x;
  int tid = threadIdx.x;
  int j   = tid & 127;                       // position in chunk
  int ng  = tid >> 7;                        // n-group {0..3}
  // ---- W fp32 -> bf16: threads 0..127 convert one float4 each ----
  if (tid < 128) {
    int i = h * 128 + tid;
    float4 v = *(const float4*)&W[i * 4];
    uint2 p; p.x = packbf(v.x, v.y); p.y = packbf(v.z, v.w);
    *(uint2*)&Wb[i * 4] = p;
  }
  float dt = __expf(log_dt[h]);
  float kacc = 0.f;
  unsigned short* Erow = Eb + (h * 128 + j) * 64;
  for (int nn = 0; nn < 8; nn++) {
    int n  = ng * 8 + nn;
    int hn = (h << 5) + n;
    float Ar = -__expf(lar[hn]), Ai = aim[hn];
    float dAr = Ar * dt, dAi = Ai * dt;
    float er = __expf(dAr);
    float sw = __sinf(dAi), cw = __cosf(dAi);
    float wr = er * cw, wi = er * sw;
    float emr = wr - 1.f, emi = wi;
    float inv = 1.f / (Ar * Ar + Ai * Ai);
    float qr = (emr * Ar + emi * Ai) * inv;
    float qi = (emi * Ar - emr * Ai) * inv;
    float Cr = C[2 * hn], Ci = C[2 * hn + 1];
    float c2r = 2.f * (Cr * qr - Ci * qi);    // 2*Ct
    float c2i = 2.f * (Cr * qi + Ci * qr);
    // k[j] += Re(2Ct * w^j)
    float ej = __expf(dAr * (float)j);
    float sj = __sinf(dAi * (float)j), cj = __cosf(dAi * (float)j);
    kacc = fmaf(c2r, ej * cj, fmaf(-c2i, ej * sj, kacc));
    // E[j][2n] = Re(2Ct w^{j+1}), E[j][2n+1] = -Im(2Ct w^{j+1})
    float e1 = __expf(dAr * (float)(j + 1));
    float s1 = __sinf(dAi * (float)(j + 1)), c1 = __cosf(dAi * (float)(j + 1));
    float w1r = e1 * c1, w1i = e1 * s1;
    Erow[2 * n]     = f2bf(c2r * w1r - c2i * w1i);
    Erow[2 * n + 1] = f2bf(-(c2r * w1i + c2i * w1r));
    // V[2n][j] = Re(w^{127-j}), V[2n+1][j] = Im(w^{127-j})
    float ev = __expf(dAr * (float)(127 - j));
    float sv = __sinf(dAi * (float)(127 - j)), cv = __cosf(dAi * (float)(127 - j));
    Vb[(h * 64 + 2 * n) * 128 + j]     = f2bf(ev * cv);
    Vb[(h * 64 + 2 * n + 1) * 128 + j] = f2bf(ev * sv);
    // chunk propagator wL = w^128 (one thread per n) -> removes ALL transcendentals
    // from k_ssm's serial prefix phase
    if (j == 0) {
      float eL = __expf(dAr * 128.f);
      float sL = __sinf(dAi * 128.f), cL = __cosf(dAi * 128.f);
      WLb[(h << 6) + 2 * n]     = eL * cL;
      WLb[(h << 6) + 2 * n + 1] = eL * sL;
    }
  }
  if (ng) kpart[ng - 1][j] = kacc;
  __syncthreads();
  if (ng == 0) kbuf[j] = f2bf(kacc + kpart[0][j] + kpart[1][j] + kpart[2][j]);
  __syncthreads();
  // Toeplitz row j: Tb[h][j][m] = kbuf[j-m] (j>=m) else 0; ng-groups split the 16 chunks
  unsigned short* Trow = Tb + (h * 128 + j) * 128;
#pragma unroll
  for (int s8i = 0; s8i < 4; s8i++) {
    int s8 = ng * 4 + s8i;
    u16x8 v;
#pragma unroll
    for (int t = 0; t < 8; t++) {
      int m = s8 * 8 + t;
      v[t] = (j >= m) ? kbuf[j - m] : (unsigned short)0;
    }
    *(u16x8*)&Trow[s8 * 8] = v;
  }
}

// ---------------- K1: fused SSM: states + prefix + emit, one block per (b,h) ----------------
// Block = 256 thr = 4 waves. R4 structure + overlap restructure:
//  * The emit GEMM's T-part (ksi 0..3) depends only on Ub/Tb, NOT on the prefix.
//    So after the phase-2 barrier, wave 0 runs the serial prefix while waves 1-3
//    run their T-part MFMAs; ONE barrier before the E-part (which reads the packed
//    incoming states). The triangular skip already gives wave 0 the LEAST T-work
//    (2 kept K-blocks vs wave 3's 8) -> prefix owner has the most slack.
//  * Prefix accesses Fb through a u32 view for BOTH reads and the packed write
//    (same TBAA type => compiler preserves read-before-write order; the old
//    per-iteration sched_barrier(0) serialized the loop at ~150cy/iter).
//  * WLb propagator loads hoisted to kernel entry (latency hides under phases 1-2).
// XCD mapping: h = g & 255 => all 8 batch-copies of an h share an XCD; per-XCD
// T/E/V working set = 2MB (L2-resident, warm from k_prep).
__global__ __launch_bounds__(256, 8) void k_ssm(const float* __restrict__ u,
                                             const float* __restrict__ WLb,
                                             const unsigned short* __restrict__ Vb,
                                             const unsigned short* __restrict__ Tb,
                                             const unsigned short* __restrict__ Eb,
                                             const float* __restrict__ Dp,
                                             unsigned short* __restrict__ yb) {
  __shared__ __align__(16) unsigned short Ub[32][136];  // row stride 272 B (17*16)
  __shared__ __align__(16) float          Fb[32][68];   // fp32 chunk-final states;
                                                        // u32 cols 0..31 become packed
                                                        // bf16 incoming states (prefix)
  int g   = blockIdx.x;
  int h   = g & 255, b = g >> 8;           // same-h blocks share an XCD -> T/E/V L2 reuse
  int tid = threadIdx.x;
  int wv = tid >> 6, lane = tid & 63;
  int n16 = lane & 15, quad = lane >> 4;
  const float* ubase = u + (b * 256 + h) * 4096;

  // wave0's prefix propagator, loaded early so L2 latency hides under phases 1-2
  float wLr = 0.f, wLi = 0.f;
  if (wv == 0 && lane < 32) {
    wLr = WLb[(h << 6) + 2 * lane];
    wLi = WLb[(h << 6) + 2 * lane + 1];
  }

  // ---- phase 1: stage u (coalesced float4 pairs -> bf16 LDS) ----
#pragma unroll
  for (int i = 0; i < 2; i++) {
    int idx = tid * 2 + i;                  // 0..511 float8s
    float4 va = *(const float4*)(ubase + idx * 8);
    float4 vb4 = *(const float4*)(ubase + idx * 8 + 4);
    unsigned short* dst = &Ub[idx >> 4][(idx & 15) * 8];
    *(unsigned int*)(dst)     = packbf(va.x, va.y);
    *(unsigned int*)(dst + 2) = packbf(va.z, va.w);
    *(unsigned int*)(dst + 4) = packbf(vb4.x, vb4.y);
    *(unsigned int*)(dst + 6) = packbf(vb4.z, vb4.w);
  }
  __syncthreads();

  // ---- phase 2: state GEMM (M=32 c, N=64 p, K=128 j); wave wv owns p-tile wv ----
  {
    f32x4 sacc[2] = {};
#pragma unroll
    for (int ks = 0; ks < 128; ks += 32) {
      int kc = ks + quad * 8;
      bf16x8 bv = *(const bf16x8*)&Vb[(h * 64 + wv * 16 + n16) * 128 + kc];
#pragma unroll
      for (int mt = 0; mt < 2; mt++) {
        bf16x8 av = *(const bf16x8*)&Ub[mt * 16 + n16][kc];
        sacc[mt] = __builtin_amdgcn_mfma_f32_16x16x32_bf16(av, bv, sacc[mt], 0, 0, 0);
      }
    }
#pragma unroll
    for (int mt = 0; mt < 2; mt++)
#pragma unroll
      for (int reg = 0; reg < 4; reg++)
        Fb[mt * 16 + quad * 4 + reg][wv * 16 + n16] = sacc[mt][reg];
  }
  __syncthreads();

  f32x4 acc[2][2] = {};                     // [mt][ntl]

  // ---- phase 3 (wave 0 only): serial prefix, overlapped with waves 1-3's T-part ----
  // u32-typed reads AND write (same TBAA type -> may-alias -> order preserved);
  // recurrence chain is just 2 fmafs/iter, LDS reads pipeline freely.
  if (wv == 0 && lane < 32) {
    int n = lane;
    unsigned int* Fbu = (unsigned int*)&Fb[0][0];   // row stride 68 u32
    float fr = 0.f, fi = 0.f;
    for (int c = 0; c < NCH; c++) {
      float sr = u2f(Fbu[c * 68 + 2 * n]);
      float si = u2f(Fbu[c * 68 + 2 * n + 1]);
      Fbu[c * 68 + n] = packbf(fr, fi);             // incoming state for chunk c
      float nr = fmaf(wLr, fr, fmaf(-wLi, fi, sr));
      float ni = fmaf(wLr, fi, fmaf(wLi, fr, si));
      fr = nr; fi = ni;
    }
  }

  // ---- phase 4a: emit GEMM T-part (ksi 0..3, reads Ub/Tb only — prefix-independent) ----
#pragma unroll
  for (int ksi = 0; ksi < 4; ksi++) {
    int kc = ksi * 32 + quad * 8;
    bf16x8 a2[2];
#pragma unroll
    for (int mt = 0; mt < 2; mt++)
      a2[mt] = *(const bf16x8*)&Ub[mt * 16 + n16][kc];
#pragma unroll
    for (int ntl = 0; ntl < 2; ntl++) {
      // triangular skip: K-block [32ksi, 32ksi+31] vs j-tile max 16(2wv+ntl)+15 —
      // entirely in the zero region iff 2*ksi > 2*wv+ntl (exact; wave-uniform).
      if (2 * ksi > 2 * wv + ntl) continue;
      int j = (wv * 2 + ntl) * 16 + n16;
      bf16x8 bv = *(const bf16x8*)&Tb[(h * 128 + j) * 128 + kc];
#pragma unroll
      for (int mt = 0; mt < 2; mt++)
        acc[mt][ntl] = __builtin_amdgcn_mfma_f32_16x16x32_bf16(a2[mt], bv, acc[mt][ntl], 0, 0, 0);
    }
  }
  __syncthreads();

  // ---- phase 4b: emit GEMM E-part (ksi 4..5, reads packed incoming states) ----
#pragma unroll
  for (int ksi = 4; ksi < 6; ksi++) {
    int kc2 = (ksi - 4) * 32 + quad * 8;            // 0..63 within packed F row
    bf16x8 a2[2];
#pragma unroll
    for (int mt = 0; mt < 2; mt++)
      a2[mt] = *(const bf16x8*)((const unsigned short*)&Fb[mt * 16 + n16][0] + kc2);
#pragma unroll
    for (int ntl = 0; ntl < 2; ntl++) {
      int j = (wv * 2 + ntl) * 16 + n16;
      bf16x8 bv = *(const bf16x8*)&Eb[(h * 128 + j) * 64 + kc2];
#pragma unroll
      for (int mt = 0; mt < 2; mt++)
        acc[mt][ntl] = __builtin_amdgcn_mfma_f32_16x16x32_bf16(a2[mt], bv, acc[mt][ntl], 0, 0, 0);
    }
  }

  // ---- phase 5: epilogue — skip, tanh-GELU (== v*sigmoid(2t)), store bf16 ----
  float Dh = Dp[h];
  unsigned short* ybase = yb + (b * 256 + h) * 4096;
#pragma unroll
  for (int mt = 0; mt < 2; mt++) {
#pragma unroll
    for (int reg = 0; reg < 4; reg++) {
      int c = mt * 16 + quad * 4 + reg;
#pragma unroll
      for (int ntl = 0; ntl < 2; ntl++) {
        int j = (wv * 2 + ntl) * 16 + n16;
        float uv = bf2f(Ub[c][j]);
        float v  = fmaf(Dh, uv, acc[mt][ntl][reg]);
        // tanh-GELU: 0.5v(1+tanh(t)) = v*sigmoid(2t), t = 0.79788456*v*(1+0.044715 v^2)
        float t2 = 1.5957691216057308f * v * fmaf(0.044715f, v * v, 1.0f);
        float ge = v / (1.0f + __expf(-t2));
        ybase[c * 128 + j] = f2bf(ge);
      }
    }
  }
}

// ---------------- K4: MFMA bf16 GEMM: z = W@y + b ; out = a * sigmoid(g) ----------------
// A-operand (W) read DIRECT from global per fragment (Wb 256KB, L2-resident, shared by
// all blocks on the XCD). Ys double-buffered; next K-step's y loads issued right after
// the barrier so latency hides under MFMA; ONE barrier per K-step.
// Staging transposes via k-PAIRED u32 stores (16 dword stores vs 32 b16 stores):
// thread owns rows (k0,k0+1) x 16 l's; store (y[k0][l],y[k0+1][l]) as one u32 to
// Ys[l][k0]. Bank check: lanes 0..31 hit 32 distinct banks; lanes 32..63 alias them
// 2-way (free).
__global__ __launch_bounds__(256) void k_gemm(const unsigned short* __restrict__ yb,
                                              const unsigned short* __restrict__ Wb,
                                              const float* __restrict__ bias,
                                              float* __restrict__ out) {
  __shared__ unsigned short Ys[2][128][72];
  int tid  = threadIdx.x;
  int l0   = blockIdx.x * 128;
  int o0   = blockIdx.y * 64;
  int bb   = blockIdx.z;
  int wave = tid >> 6;
  int lane = tid & 63;
  int wo   = wave & 1;
  int wl   = wave >> 1;
  int n    = lane & 15;
  int quad = lane >> 4;
  int kp   = (tid & 31) * 2;     // k-pair base: 0,2,..,62
  int lg   = tid >> 5;           // l-group 0..7 (16 l's each)

  f32x4 acc_a[2][4] = {};
  f32x4 acc_g[2][4] = {};

  u16x8 y0a, y0b, y1a, y1b;      // rows kp, kp+1 at l = lg*16..lg*16+15
  {
    const unsigned short* yr = yb + (size_t)(bb * 256 + kp) * 4096 + l0 + lg * 16;
    y0a = *(const u16x8*)&yr[0];     y0b = *(const u16x8*)&yr[8];
    y1a = *(const u16x8*)&yr[4096];  y1b = *(const u16x8*)&yr[4096 + 8];
  }

#pragma unroll
  for (int kk = 0; kk < H; kk += 64) {
    int cur = (kk >> 6) & 1;
    // k-paired transpose-write into Ys[cur]
#pragma unroll
    for (int t = 0; t < 8; t++) {
      *(unsigned int*)&Ys[cur][lg * 16 + t][kp] =
          (unsigned int)(unsigned short)y0a[t] | ((unsigned int)(unsigned short)y1a[t] << 16);
      *(unsigned int*)&Ys[cur][lg * 16 + 8 + t][kp] =
          (unsigned int)(unsigned short)y0b[t] | ((unsigned int)(unsigned short)y1b[t] << 16);
    }
    __syncthreads();
    // issue next K-step's y loads; latency hides under the MFMAs below
    if (kk + 64 < H) {
      const unsigned short* yr = yb + (size_t)(bb * 256 + kk + 64 + kp) * 4096 + l0 + lg * 16;
      y0a = *(const u16x8*)&yr[0];     y0b = *(const u16x8*)&yr[8];
      y1a = *(const u16x8*)&yr[4096];  y1b = *(const u16x8*)&yr[4096 + 8];
    }
#pragma unroll
    for (int ks = 0; ks < 64; ks += 32) {
      int kc = ks + quad * 8;
      bf16x8 af_a[2], af_g[2], bfr[4];
#pragma unroll
      for (int mt = 0; mt < 2; mt++) {
        int oa = o0 + wo * 32 + mt * 16 + n;
        af_a[mt] = *(const bf16x8*)&Wb[(size_t)oa * 256 + kk + kc];
        af_g[mt] = *(const bf16x8*)&Wb[(size_t)(256 + oa) * 256 + kk + kc];
      }
#pragma unroll
      for (int lt = 0; lt < 4; lt++)
        bfr[lt] = *(const bf16x8*)&Ys[cur][wl * 64 + lt * 16 + n][kc];
#pragma unroll
      for (int mt = 0; mt < 2; mt++)
#pragma unroll
        for (int lt = 0; lt < 4; lt++) {
          acc_a[mt][lt] = __builtin_amdgcn_mfma_f32_16x16x32_bf16(af_a[mt], bfr[lt], acc_a[mt][lt], 0, 0, 0);
          acc_g[mt][lt] = __builtin_amdgcn_mfma_f32_16x16x32_bf16(af_g[mt], bfr[lt], acc_g[mt][lt], 0, 0, 0);
        }
    }
  }
#pragma unroll
  for (int mt = 0; mt < 2; mt++) {
    int ob = o0 + wo * 32 + mt * 16 + quad * 4;
#pragma unroll
    for (int reg = 0; reg < 4; reg++) {
      int op = ob + reg;
      float ba = bias[op], bg = bias[H + op];
      float* orow = &out[(bb * H + op) * Lseq + l0 + wl * 64 + n];
#pragma unroll
      for (int lt = 0; lt < 4; lt++) {
        float a = acc_a[mt][lt][reg] + ba;
        float gg = acc_g[mt][lt][reg] + bg;
        orow[lt * 16] = a / (1.0f + __expf(-gg));
      }
    }
  }
}

extern "C" void kernel_launch(void* const* d_in, const int* in_sizes, int n_in,
                              void* d_out, int out_size, void* d_ws, size_t ws_size,
                              hipStream_t stream) {
  const float* u      = (const float*)d_in[0];
  const float* log_dt = (const float*)d_in[1];
  const float* C      = (const float*)d_in[2];
  const float* lar    = (const float*)d_in[3];
  const float* aim    = (const float*)d_in[4];
  const float* Dp     = (const float*)d_in[5];
  const float* W      = (const float*)d_in[6];
  const float* bias   = (const float*)d_in[7];
  float* out = (float*)d_out;
  float* ws  = (float*)d_ws;
  unsigned short* yb  = (unsigned short*)(ws + Y_OFF);
  unsigned short* Wb  = (unsigned short*)(ws + WB_OFF);
  unsigned short* Tbg = (unsigned short*)(ws + TB_OFF);
  unsigned short* Ebg = (unsigned short*)(ws + EB_OFF);
  unsigned short* Vbg = (unsigned short*)(ws + VB_OFF);
  float*          WLb = (float*)(ws + WL_OFF);

  hipLaunchKernelGGL(k_prep, dim3(H), dim3(512), 0, stream, log_dt, C, lar, aim, W, Wb, Tbg, Ebg, Vbg, WLb);
  hipLaunchKernelGGL(k_ssm,  dim3(BH), dim3(256), 0, stream, u, WLb, Vbg, Tbg, Ebg, Dp, yb);
  hipLaunchKernelGGL(k_gemm, dim3(Lseq / 128, H / 64, Bsz), dim3(256), 0, stream, yb, Wb, bias, out);
}

// Round 6
// 144.236 us; speedup vs baseline: 1.0081x; 1.0081x over previous
//
#include <hip/hip_runtime.h>
#include <math.h>

#define H 256
#define N2 32
#define Bsz 8
#define Lseq 4096
#define BH (Bsz*H)          // 2048 sequences
#define NCH 32              // chunks along L
#define LC (Lseq/NCH)       // 128 chunk length
#define HN (H*N2)           // 8192

// workspace layout (float slots):
//  yb : BH*Lseq bf16        post-GELU activations
//  Wb : 512*256 bf16        pre-converted W
//  Tb : H*128*128 bf16      Toeplitz conv matrix T[h][j][m] = k[h][j-m] (0 if j<m)
//  Eb : H*128*64 bf16       emission basis E[h][j][p]   (j-major, p-contig)
//  Vb : H*64*128 bf16       state basis  V[h][p][j]     (p-major, j-contig)
//  WL : H*64 f32            per-(h,n) chunk propagator wL = w^128 (re,im pairs)
#define Y_OFF  0
#define WB_OFF (Y_OFF + (BH*Lseq/2))
#define TB_OFF (WB_OFF + (512*256/2))
#define EB_OFF (TB_OFF + (H*128*128/2))
#define VB_OFF (EB_OFF + (H*128*64/2))
#define WL_OFF (VB_OFF + (H*64*128/2))

typedef __attribute__((ext_vector_type(8))) short bf16x8;
typedef __attribute__((ext_vector_type(8))) unsigned short u16x8;
typedef __attribute__((ext_vector_type(4))) float f32x4;

__device__ __forceinline__ unsigned short f2bf(float x) {
  union { float f; unsigned int u; } v; v.f = x;
  unsigned int r = v.u + 0x7fffu + ((v.u >> 16) & 1u);  // round-to-nearest-even
  return (unsigned short)(r >> 16);
}
__device__ __forceinline__ unsigned int packbf(float lo, float hi) {
  return (unsigned int)f2bf(lo) | ((unsigned int)f2bf(hi) << 16);
}
__device__ __forceinline__ float bf2f(unsigned short b) {
  union { unsigned int u; float f; } v; v.u = ((unsigned int)b) << 16;
  return v.f;
}
__device__ __forceinline__ float u2f(unsigned int u) {
  union { unsigned int u; float f; } v; v.u = u; return v.f;
}

// ---------------- K0: prep — W->bf16, Toeplitz Tb, bases Eb & Vb, propagator WL ----------------
// grid 256 (h), block 512 = (j 0..127) x (ng 0..3); 8 waves/block = 2 waves/SIMD.
// Native transcendentals throughout. Per (n,j) only ONE exp/sin/cos set (w^j):
//  - k[j] uses w^j directly;
//  - E row needs w^{j+1} = w^j * w (4 mults, no transcendentals);
//  - V slot 127-j needs w^j  => thread j writes V at index 127-j (bit-identical
//    values to the old direct computation, just written by a different thread;
//    reversed-contiguous 2B stores still fall in the same 128B segment).
// 13 -> 7 transcendentals per n-iteration.
__global__ __launch_bounds__(512) void k_prep(const float* __restrict__ log_dt,
                                              const float* __restrict__ C,
                                              const float* __restrict__ lar,
                                              const float* __restrict__ aim,
                                              const float* __restrict__ W,
                                              unsigned short* __restrict__ Wb,
                                              unsigned short* __restrict__ Tb,
                                              unsigned short* __restrict__ Eb,
                                              unsigned short* __restrict__ Vb,
                                              float* __restrict__ WLb) {
  __shared__ float kpart[3][128];
  __shared__ unsigned short kbuf[128];
  int h   = blockIdx.x;
  int tid = threadIdx.x;
  int j   = tid & 127;                       // position in chunk
  int ng  = tid >> 7;                        // n-group {0..3}
  // ---- W fp32 -> bf16: threads 0..127 convert one float4 each ----
  if (tid < 128) {
    int i = h * 128 + tid;
    float4 v = *(const float4*)&W[i * 4];
    uint2 p; p.x = packbf(v.x, v.y); p.y = packbf(v.z, v.w);
    *(uint2*)&Wb[i * 4] = p;
  }
  float dt = __expf(log_dt[h]);
  float kacc = 0.f;
  unsigned short* Erow = Eb + (h * 128 + j) * 64;
  for (int nn = 0; nn < 8; nn++) {
    int n  = ng * 8 + nn;
    int hn = (h << 5) + n;
    float Ar = -__expf(lar[hn]), Ai = aim[hn];
    float dAr = Ar * dt, dAi = Ai * dt;
    float er = __expf(dAr);
    float sw = __sinf(dAi), cw = __cosf(dAi);
    float wr_ = er * cw, wi_ = er * sw;       // w
    float emr = wr_ - 1.f, emi = wi_;
    float inv = 1.f / (Ar * Ar + Ai * Ai);
    float qr = (emr * Ar + emi * Ai) * inv;
    float qi = (emi * Ar - emr * Ai) * inv;
    float Cr = C[2 * hn], Ci = C[2 * hn + 1];
    float c2r = 2.f * (Cr * qr - Ci * qi);    // 2*Ct
    float c2i = 2.f * (Cr * qi + Ci * qr);
    // w^j — the only per-j transcendental set
    float ej = __expf(dAr * (float)j);
    float sj = __sinf(dAi * (float)j), cj = __cosf(dAi * (float)j);
    float wjr = ej * cj, wji = ej * sj;
    // k[j] += Re(2Ct * w^j)
    kacc = fmaf(c2r, wjr, fmaf(-c2i, wji, kacc));
    // E[j][2n] = Re(2Ct w^{j+1}), E[j][2n+1] = -Im(2Ct w^{j+1});  w^{j+1} = w^j * w
    float w1r = wjr * wr_ - wji * wi_;
    float w1i = wjr * wi_ + wji * wr_;
    Erow[2 * n]     = f2bf(c2r * w1r - c2i * w1i);
    Erow[2 * n + 1] = f2bf(-(c2r * w1i + c2i * w1r));
    // V[2n][127-j] = Re(w^j), V[2n+1][127-j] = Im(w^j)   (slot jj holds w^{127-jj})
    Vb[(h * 64 + 2 * n) * 128 + (127 - j)]     = f2bf(wjr);
    Vb[(h * 64 + 2 * n + 1) * 128 + (127 - j)] = f2bf(wji);
    // chunk propagator wL = w^128 (one thread per n) — k_ssm prefix has no transcendentals
    if (j == 0) {
      float eL = __expf(dAr * 128.f);
      float sL = __sinf(dAi * 128.f), cL = __cosf(dAi * 128.f);
      WLb[(h << 6) + 2 * n]     = eL * cL;
      WLb[(h << 6) + 2 * n + 1] = eL * sL;
    }
  }
  if (ng) kpart[ng - 1][j] = kacc;
  __syncthreads();
  if (ng == 0) kbuf[j] = f2bf(kacc + kpart[0][j] + kpart[1][j] + kpart[2][j]);
  __syncthreads();
  // Toeplitz row j: Tb[h][j][m] = kbuf[j-m] (j>=m) else 0; ng-groups split the 16 chunks
  unsigned short* Trow = Tb + (h * 128 + j) * 128;
#pragma unroll
  for (int s8i = 0; s8i < 4; s8i++) {
    int s8 = ng * 4 + s8i;
    u16x8 v;
#pragma unroll
    for (int t = 0; t < 8; t++) {
      int m = s8 * 8 + t;
      v[t] = (j >= m) ? kbuf[j - m] : (unsigned short)0;
    }
    *(u16x8*)&Trow[s8 * 8] = v;
  }
}

// ---------------- K1: fused SSM: states + prefix + emit, one block per (b,h) ----------------
// FROZEN since R5 (structural changes proved neutral; kernel is near its ~10µs HBM floor).
// Block = 256 thr = 4 waves; overlap: wave 0 runs the serial prefix while waves 1-3
// run their T-part MFMAs; triangular skip removes 11/32 of T-work exactly.
// XCD mapping: h = g & 255 => all 8 batch-copies of an h share an XCD; per-XCD
// T/E/V working set = 2MB (L2-resident, warm from k_prep).
__global__ __launch_bounds__(256, 8) void k_ssm(const float* __restrict__ u,
                                             const float* __restrict__ WLb,
                                             const unsigned short* __restrict__ Vb,
                                             const unsigned short* __restrict__ Tb,
                                             const unsigned short* __restrict__ Eb,
                                             const float* __restrict__ Dp,
                                             unsigned short* __restrict__ yb) {
  __shared__ __align__(16) unsigned short Ub[32][136];  // row stride 272 B (17*16)
  __shared__ __align__(16) float          Fb[32][68];   // fp32 chunk-final states;
                                                        // u32 cols 0..31 become packed
                                                        // bf16 incoming states (prefix)
  int g   = blockIdx.x;
  int h   = g & 255, b = g >> 8;           // same-h blocks share an XCD -> T/E/V L2 reuse
  int tid = threadIdx.x;
  int wv = tid >> 6, lane = tid & 63;
  int n16 = lane & 15, quad = lane >> 4;
  const float* ubase = u + (b * 256 + h) * 4096;

  // wave0's prefix propagator, loaded early so L2 latency hides under phases 1-2
  float wLr = 0.f, wLi = 0.f;
  if (wv == 0 && lane < 32) {
    wLr = WLb[(h << 6) + 2 * lane];
    wLi = WLb[(h << 6) + 2 * lane + 1];
  }

  // ---- phase 1: stage u (coalesced float4 pairs -> bf16 LDS) ----
#pragma unroll
  for (int i = 0; i < 2; i++) {
    int idx = tid * 2 + i;                  // 0..511 float8s
    float4 va = *(const float4*)(ubase + idx * 8);
    float4 vb4 = *(const float4*)(ubase + idx * 8 + 4);
    unsigned short* dst = &Ub[idx >> 4][(idx & 15) * 8];
    *(unsigned int*)(dst)     = packbf(va.x, va.y);
    *(unsigned int*)(dst + 2) = packbf(va.z, va.w);
    *(unsigned int*)(dst + 4) = packbf(vb4.x, vb4.y);
    *(unsigned int*)(dst + 6) = packbf(vb4.z, vb4.w);
  }
  __syncthreads();

  // ---- phase 2: state GEMM (M=32 c, N=64 p, K=128 j); wave wv owns p-tile wv ----
  {
    f32x4 sacc[2] = {};
#pragma unroll
    for (int ks = 0; ks < 128; ks += 32) {
      int kc = ks + quad * 8;
      bf16x8 bv = *(const bf16x8*)&Vb[(h * 64 + wv * 16 + n16) * 128 + kc];
#pragma unroll
      for (int mt = 0; mt < 2; mt++) {
        bf16x8 av = *(const bf16x8*)&Ub[mt * 16 + n16][kc];
        sacc[mt] = __builtin_amdgcn_mfma_f32_16x16x32_bf16(av, bv, sacc[mt], 0, 0, 0);
      }
    }
#pragma unroll
    for (int mt = 0; mt < 2; mt++)
#pragma unroll
      for (int reg = 0; reg < 4; reg++)
        Fb[mt * 16 + quad * 4 + reg][wv * 16 + n16] = sacc[mt][reg];
  }
  __syncthreads();

  f32x4 acc[2][2] = {};                     // [mt][ntl]

  // ---- phase 3 (wave 0 only): serial prefix, overlapped with waves 1-3's T-part ----
  if (wv == 0 && lane < 32) {
    int n = lane;
    unsigned int* Fbu = (unsigned int*)&Fb[0][0];   // row stride 68 u32
    float fr = 0.f, fi = 0.f;
    for (int c = 0; c < NCH; c++) {
      float sr = u2f(Fbu[c * 68 + 2 * n]);
      float si = u2f(Fbu[c * 68 + 2 * n + 1]);
      Fbu[c * 68 + n] = packbf(fr, fi);             // incoming state for chunk c
      float nr = fmaf(wLr, fr, fmaf(-wLi, fi, sr));
      float ni = fmaf(wLr, fi, fmaf(wLi, fr, si));
      fr = nr; fi = ni;
    }
  }

  // ---- phase 4a: emit GEMM T-part (ksi 0..3, reads Ub/Tb only — prefix-independent) ----
#pragma unroll
  for (int ksi = 0; ksi < 4; ksi++) {
    int kc = ksi * 32 + quad * 8;
    bf16x8 a2[2];
#pragma unroll
    for (int mt = 0; mt < 2; mt++)
      a2[mt] = *(const bf16x8*)&Ub[mt * 16 + n16][kc];
#pragma unroll
    for (int ntl = 0; ntl < 2; ntl++) {
      // triangular skip: exact, wave-uniform
      if (2 * ksi > 2 * wv + ntl) continue;
      int j = (wv * 2 + ntl) * 16 + n16;
      bf16x8 bv = *(const bf16x8*)&Tb[(h * 128 + j) * 128 + kc];
#pragma unroll
      for (int mt = 0; mt < 2; mt++)
        acc[mt][ntl] = __builtin_amdgcn_mfma_f32_16x16x32_bf16(a2[mt], bv, acc[mt][ntl], 0, 0, 0);
    }
  }
  __syncthreads();

  // ---- phase 4b: emit GEMM E-part (ksi 4..5, reads packed incoming states) ----
#pragma unroll
  for (int ksi = 4; ksi < 6; ksi++) {
    int kc2 = (ksi - 4) * 32 + quad * 8;            // 0..63 within packed F row
    bf16x8 a2[2];
#pragma unroll
    for (int mt = 0; mt < 2; mt++)
      a2[mt] = *(const bf16x8*)((const unsigned short*)&Fb[mt * 16 + n16][0] + kc2);
#pragma unroll
    for (int ntl = 0; ntl < 2; ntl++) {
      int j = (wv * 2 + ntl) * 16 + n16;
      bf16x8 bv = *(const bf16x8*)&Eb[(h * 128 + j) * 64 + kc2];
#pragma unroll
      for (int mt = 0; mt < 2; mt++)
        acc[mt][ntl] = __builtin_amdgcn_mfma_f32_16x16x32_bf16(a2[mt], bv, acc[mt][ntl], 0, 0, 0);
    }
  }

  // ---- phase 5: epilogue — skip, tanh-GELU (== v*sigmoid(2t)), store bf16 ----
  float Dh = Dp[h];
  unsigned short* ybase = yb + (b * 256 + h) * 4096;
#pragma unroll
  for (int mt = 0; mt < 2; mt++) {
#pragma unroll
    for (int reg = 0; reg < 4; reg++) {
      int c = mt * 16 + quad * 4 + reg;
#pragma unroll
      for (int ntl = 0; ntl < 2; ntl++) {
        int j = (wv * 2 + ntl) * 16 + n16;
        float uv = bf2f(Ub[c][j]);
        float v  = fmaf(Dh, uv, acc[mt][ntl][reg]);
        float t2 = 1.5957691216057308f * v * fmaf(0.044715f, v * v, 1.0f);
        float ge = v / (1.0f + __expf(-t2));
        ybase[c * 128 + j] = f2bf(ge);
      }
    }
  }
}

// ---------------- K4: MFMA bf16 GEMM: z = W@y + b ; out = a * sigmoid(g) ----------------
// OPERANDS SWAPPED vs R5: acc = mfma(y_frag, W_frag) -> D[m=l][n=op]. A/B fragment
// layouts are symmetric transposes, so the SAME register data serves both roles; the
// C/D layout then gives each lane 4 CONSECUTIVE l (reg) at fixed op -> epilogue is
// 8x global_store_dwordx4 (was 32 scalar dwords), each instruction covering
// 16 rows x 64B contiguous. W direct from L2-resident Wb; Ys double-buffered with
// post-barrier prefetch; ONE barrier per K-step.
__global__ __launch_bounds__(256) void k_gemm(const unsigned short* __restrict__ yb,
                                              const unsigned short* __restrict__ Wb,
                                              const float* __restrict__ bias,
                                              float* __restrict__ out) {
  __shared__ unsigned short Ys[2][128][72];
  int tid  = threadIdx.x;
  int l0   = blockIdx.x * 128;
  int o0   = blockIdx.y * 64;
  int bb   = blockIdx.z;
  int wave = tid >> 6;
  int lane = tid & 63;
  int wo   = wave & 1;
  int wl   = wave >> 1;
  int n    = lane & 15;
  int quad = lane >> 4;
  int kp   = (tid & 31) * 2;     // k-pair base: 0,2,..,62
  int lg   = tid >> 5;           // l-group 0..7 (16 l's each)

  f32x4 acc_a[2][4] = {};        // [mt=op-tile][lt=l-tile]
  f32x4 acc_g[2][4] = {};

  u16x8 y0a, y0b, y1a, y1b;      // rows kp, kp+1 at l = lg*16..lg*16+15
  {
    const unsigned short* yr = yb + (size_t)(bb * 256 + kp) * 4096 + l0 + lg * 16;
    y0a = *(const u16x8*)&yr[0];     y0b = *(const u16x8*)&yr[8];
    y1a = *(const u16x8*)&yr[4096];  y1b = *(const u16x8*)&yr[4096 + 8];
  }

#pragma unroll
  for (int kk = 0; kk < H; kk += 64) {
    int cur = (kk >> 6) & 1;
    // k-paired transpose-write into Ys[cur]
#pragma unroll
    for (int t = 0; t < 8; t++) {
      *(unsigned int*)&Ys[cur][lg * 16 + t][kp] =
          (unsigned int)(unsigned short)y0a[t] | ((unsigned int)(unsigned short)y1a[t] << 16);
      *(unsigned int*)&Ys[cur][lg * 16 + 8 + t][kp] =
          (unsigned int)(unsigned short)y0b[t] | ((unsigned int)(unsigned short)y1b[t] << 16);
    }
    __syncthreads();
    // issue next K-step's y loads; latency hides under the MFMAs below
    if (kk + 64 < H) {
      const unsigned short* yr = yb + (size_t)(bb * 256 + kk + 64 + kp) * 4096 + l0 + lg * 16;
      y0a = *(const u16x8*)&yr[0];     y0b = *(const u16x8*)&yr[8];
      y1a = *(const u16x8*)&yr[4096];  y1b = *(const u16x8*)&yr[4096 + 8];
    }
#pragma unroll
    for (int ks = 0; ks < 64; ks += 32) {
      int kc = ks + quad * 8;
      bf16x8 af_a[2], af_g[2], bfr[4];
#pragma unroll
      for (int mt = 0; mt < 2; mt++) {
        int oa = o0 + wo * 32 + mt * 16 + n;
        af_a[mt] = *(const bf16x8*)&Wb[(size_t)oa * 256 + kk + kc];
        af_g[mt] = *(const bf16x8*)&Wb[(size_t)(256 + oa) * 256 + kk + kc];
      }
#pragma unroll
      for (int lt = 0; lt < 4; lt++)
        bfr[lt] = *(const bf16x8*)&Ys[cur][wl * 64 + lt * 16 + n][kc];
      // swapped operands: A = y (M=l), B = W (N=op)
#pragma unroll
      for (int mt = 0; mt < 2; mt++)
#pragma unroll
        for (int lt = 0; lt < 4; lt++) {
          acc_a[mt][lt] = __builtin_amdgcn_mfma_f32_16x16x32_bf16(bfr[lt], af_a[mt], acc_a[mt][lt], 0, 0, 0);
          acc_g[mt][lt] = __builtin_amdgcn_mfma_f32_16x16x32_bf16(bfr[lt], af_g[mt], acc_g[mt][lt], 0, 0, 0);
        }
    }
  }
  // epilogue: lane holds rows l = quad*4+reg (consecutive), col op = n -> float4 stores
#pragma unroll
  for (int mt = 0; mt < 2; mt++) {
    int op = o0 + wo * 32 + mt * 16 + n;
    float ba = bias[op], bg = bias[H + op];
    float* obase = &out[((size_t)bb * H + op) * Lseq + l0 + wl * 64 + quad * 4];
#pragma unroll
    for (int lt = 0; lt < 4; lt++) {
      float4 v;
#pragma unroll
      for (int reg = 0; reg < 4; reg++) {
        float a  = acc_a[mt][lt][reg] + ba;
        float gg = acc_g[mt][lt][reg] + bg;
        ((float*)&v)[reg] = a / (1.0f + __expf(-gg));
      }
      *(float4*)&obase[lt * 16] = v;
    }
  }
}

extern "C" void kernel_launch(void* const* d_in, const int* in_sizes, int n_in,
                              void* d_out, int out_size, void* d_ws, size_t ws_size,
                              hipStream_t stream) {
  const float* u      = (const float*)d_in[0];
  const float* log_dt = (const float*)d_in[1];
  const float* C      = (const float*)d_in[2];
  const float* lar    = (const float*)d_in[3];
  const float* aim    = (const float*)d_in[4];
  const float* Dp     = (const float*)d_in[5];
  const float* W      = (const float*)d_in[6];
  const float* bias   = (const float*)d_in[7];
  float* out = (float*)d_out;
  float* ws  = (float*)d_ws;
  unsigned short* yb  = (unsigned short*)(ws + Y_OFF);
  unsigned short* Wb  = (unsigned short*)(ws + WB_OFF);
  unsigned short* Tbg = (unsigned short*)(ws + TB_OFF);
  unsigned short* Ebg = (unsigned short*)(ws + EB_OFF);
  unsigned short* Vbg = (unsigned short*)(ws + VB_OFF);
  float*          WLb = (float*)(ws + WL_OFF);

  hipLaunchKernelGGL(k_prep, dim3(H), dim3(512), 0, stream, log_dt, C, lar, aim, W, Wb, Tbg, Ebg, Vbg, WLb);
  hipLaunchKernelGGL(k_ssm,  dim3(BH), dim3(256), 0, stream, u, WLb, Vbg, Tbg, Ebg, Dp, yb);
  hipLaunchKernelGGL(k_gemm, dim3(Lseq / 128, H / 64, Bsz), dim3(256), 0, stream, yb, Wb, bias, out);
}